// Round 9
// baseline (208.273 us; speedup 1.0000x reference)
//
#include <hip/hip_runtime.h>
#include <hip/hip_bf16.h>
#include <math.h>

// Problem constants (from reference)
constexpr int   NC      = 181;        // NUM_CLASSES
constexpr int   BATCH   = 131072;
constexpr float MODC    = 6.2831853071795864769f;   // 2*pi
constexpr float HALFMOD = 3.1415926535897932385f;   // pi
constexpr float DEG2RAD = 0.017453292519943295f;    // pi/180

// magic divide by 181: exact for g < 25.87M (max g here = 23,724,031)
constexpr unsigned MAGIC181 = 23729102u;

constexpr int TOT4  = BATCH * NC / 4;   // 5,931,008 int4 total (exact)
constexpr int NMASK = TOT4 / 8;         // 741,376 mask dwords

// ---------------- K1: compressing stream (copy-shaped) ----------------
// 2896 blocks x 256 threads x 8 coalesced int4. No LDS, no barriers, no
// branches, no atomics: load batch -> pack 32 nonzero bits -> 1 store.
__global__ __launch_bounds__(256) void mask_kernel(
    const int*  __restrict__ labels,
    unsigned*   __restrict__ masks)
{
    const int tid = threadIdx.x;
    const unsigned base4 = blockIdx.x * 2048u + (unsigned)tid;
    const int4* p4 = (const int4*)labels;

    int4 v[8];
    #pragma unroll
    for (int k = 0; k < 8; ++k)
        v[k] = p4[base4 + 256u * k];

    __builtin_amdgcn_sched_barrier(0);   // keep the 8-load batch intact

    unsigned m = 0u;
    #pragma unroll
    for (int k = 0; k < 8; ++k) {
        m |= ((unsigned)(v[k].x != 0)) << (4 * k + 0);
        m |= ((unsigned)(v[k].y != 0)) << (4 * k + 1);
        m |= ((unsigned)(v[k].z != 0)) << (4 * k + 2);
        m |= ((unsigned)(v[k].w != 0)) << (4 * k + 3);
    }
    masks[blockIdx.x * 256u + (unsigned)tid] = m;
}

// ---------------- K2: decode masks -> global row bitmap ----------------
// 724 blocks x 256 threads x 4 mask dwords. ~1.4 set bits / 2 dwords.
// Mask dword d, bit b (k=b>>2, c=b&3) covers int4 (d>>8)*2048+(d&255)+256k,
// int g = that*4+c. Fire-and-forget atomicOr into 4 MB bitmap.
__global__ __launch_bounds__(256) void decode_kernel(
    const unsigned* __restrict__ masks,
    unsigned*       __restrict__ bm)
{
    const unsigned base = blockIdx.x * 1024u + (unsigned)threadIdx.x;

    unsigned mw[4];
    #pragma unroll
    for (int j = 0; j < 4; ++j)
        mw[j] = masks[base + 256u * j];

    __builtin_amdgcn_sched_barrier(0);

    #pragma unroll
    for (int j = 0; j < 4; ++j) {
        const unsigned d = base + 256u * j;
        unsigned w = mw[j];
        while (w) {
            const int b = __builtin_ctz(w);
            w &= w - 1;
            const unsigned i4 = ((d >> 8) << 11) + (d & 255u)
                              + (((unsigned)b >> 2) << 8);
            const unsigned g   = i4 * 4u + ((unsigned)b & 3u);
            const unsigned row = __umulhi(g, MAGIC181);   // g / 181
            const unsigned cls = g - 181u * row;          // g % 181
            atomicOr(&bm[row * 8u + (cls >> 5u)], 1u << (cls & 31u));
        }
    }
}

// ---------------- K3: per-row perm-min + reduction (validated in R5) ----
__device__ __forceinline__ float sq_mod_diff(float x) {
    // d = mod(x + pi, 2pi) - pi;  return d*d   (floored mod, matches jnp.mod)
    float t = x + HALFMOD;
    float m = t - floorf(t * (1.0f / MODC)) * MODC;
    float d = m - HALFMOD;
    return d * d;
}

__global__ __launch_bounds__(256) void finish_kernel(
    const float*    __restrict__ logits,
    const unsigned* __restrict__ bm,
    float*          __restrict__ out)
{
    const int row = blockIdx.x * 256 + threadIdx.x;

    const uint4 w0 = ((const uint4*)bm)[(size_t)row * 2 + 0];
    const uint4 w1 = ((const uint4*)bm)[(size_t)row * 2 + 1];
    const float* lp = logits + (size_t)row * NC;
    const float doa[4] = {lp[0], lp[1], lp[2], lp[3]};

    unsigned w[8] = {w0.x, w0.y, w0.z, w0.w, w1.x, w1.y, w1.z, w1.w};
    float ang[4];
    int found = 0;
    #pragma unroll
    for (int k = 0; k < 8; ++k) {
        unsigned mm = w[k];
        while (mm) {
            const int j = __builtin_ctz(mm);
            mm &= mm - 1;
            ang[found & 3] = ((float)(k * 32 + j) - 90.0f) * DEG2RAD;
            ++found;
        }
    }

    float cst[4][4];
    #pragma unroll
    for (int i = 0; i < 4; ++i)
        #pragma unroll
        for (int j = 0; j < 4; ++j)
            cst[i][j] = sq_mod_diff(doa[i] - ang[j]);

    float best = 1e30f;
    #pragma unroll
    for (int a = 0; a < 4; ++a) {
        #pragma unroll
        for (int b = 0; b < 4; ++b) {
            if (b == a) continue;
            const float top = cst[0][a] + cst[1][b];
            #pragma unroll
            for (int e = 0; e < 4; ++e) {
                if (e == a || e == b) continue;
                const int f = 6 - a - b - e;
                best = fminf(best, top + cst[2][e] + cst[3][f]);
            }
        }
    }
    float sum = sqrtf(best * 0.25f);

    #pragma unroll
    for (int off = 32; off > 0; off >>= 1)
        sum += __shfl_down(sum, off);

    __shared__ float wsum[4];
    const int lane = threadIdx.x & 63;
    const int wv   = threadIdx.x >> 6;
    if (lane == 0) wsum[wv] = sum;
    __syncthreads();
    if (threadIdx.x == 0) {
        float t = (wsum[0] + wsum[1]) + (wsum[2] + wsum[3]);
        atomicAdd(out, t * (1.0f / (float)BATCH));
    }
}

extern "C" void kernel_launch(void* const* d_in, const int* in_sizes, int n_in,
                              void* d_out, int out_size, void* d_ws, size_t ws_size,
                              hipStream_t stream) {
    const float* logits = (const float*)d_in[0];
    const int*   labels = (const int*)d_in[1];
    float*       out    = (float*)d_out;

    unsigned* bm    = (unsigned*)d_ws;                        // 4 MB bitmap
    unsigned* masks = (unsigned*)((char*)d_ws + (size_t)BATCH * 32); // 2.9 MB

    // d_out / d_ws are poisoned (0xAA) before every launch.
    hipMemsetAsync(out, 0, sizeof(float), stream);
    hipMemsetAsync(bm, 0, (size_t)BATCH * 32, stream);
    // masks needs no init: every dword is written unconditionally by K1.

    mask_kernel  <<<2896,          256, 0, stream>>>(labels, masks);
    decode_kernel<<<NMASK / 1024,  256, 0, stream>>>(masks, bm);
    finish_kernel<<<BATCH / 256,   256, 0, stream>>>(logits, bm, out);
}

// Round 10
// 191.364 us; speedup vs baseline: 1.0884x; 1.0884x over previous
//
#include <hip/hip_runtime.h>
#include <hip/hip_bf16.h>
#include <math.h>

// Problem constants (from reference)
constexpr int   NC      = 181;        // NUM_CLASSES
constexpr int   BATCH   = 131072;
constexpr float MODC    = 6.2831853071795864769f;   // 2*pi
constexpr float HALFMOD = 3.1415926535897932385f;   // pi
constexpr float DEG2RAD = 0.017453292519943295f;    // pi/180

// magic divide by 181: exact well past window size (11584 ints)
constexpr unsigned MAGIC181 = 23729102u;

// One 256-thread block owns 64 rows = 2896 int4 of contiguous labels.
// Loads are NONTEMPORAL (bypass L2 allocation for the 95 MB single-use
// stream) and batched behind sched_barrier(0). Consumption is register-
// nibble masks -> LDS bitmap deposits; no LDS staging of raw data, and
// no barrier between load issue and use (bm-zero barrier is pre-load).
constexpr int RPB   = 64;                    // rows per block
constexpr int WINT4 = RPB * NC / 4;          // 2896 int4 per block window
constexpr int FULL  = WINT4 / 256;           // 11 full int4 per thread
constexpr int TAIL  = WINT4 - FULL * 256;    // 80 tail int4

typedef int v4i __attribute__((ext_vector_type(4)));

__device__ __forceinline__ float sq_mod_diff(float x) {
    // d = mod(x + pi, 2pi) - pi;  return d*d   (floored mod, matches jnp.mod)
    float t = x + HALFMOD;
    float m = t - floorf(t * (1.0f / MODC)) * MODC;
    float d = m - HALFMOD;
    return d * d;
}

__device__ __forceinline__ unsigned nib(v4i v) {
    return (unsigned)(v[0] != 0)
         | ((unsigned)(v[1] != 0) << 1)
         | ((unsigned)(v[2] != 0) << 2)
         | ((unsigned)(v[3] != 0) << 3);
}

__global__ __launch_bounds__(256) void fused_kernel(
    const float* __restrict__ logits,
    const int*   __restrict__ labels,
    float*       __restrict__ out)
{
    __shared__ unsigned bm[RPB * 8];    // 2 KB: 64 rows x 256-bit bitmap

    const int tid  = threadIdx.x;
    const int lane = tid & 63;

    // ---- zero LDS bitmap, then barrier BEFORE any global load issues ----
    bm[tid]       = 0u;
    bm[tid + 256] = 0u;
    __syncthreads();   // only lgkm pending here — no vmcnt drain cost

    // ---- logits prefetch (consumed in phase 3) ----
    float d0 = 0.f, d1 = 0.f, d2 = 0.f, d3 = 0.f;
    if (tid < RPB) {
        const float* lp = logits + (size_t)(blockIdx.x * RPB + tid) * NC;
        d0 = lp[0]; d1 = lp[1]; d2 = lp[2]; d3 = lp[3];
    }

    // ---- batched nontemporal label loads ----
    const v4i* gbase = (const v4i*)labels + (size_t)blockIdx.x * WINT4;
    v4i v[FULL];
    #pragma unroll
    for (int k = 0; k < FULL; ++k)
        v[k] = __builtin_nontemporal_load(gbase + tid + 256 * k);
    v4i vt = {0, 0, 0, 0};
    if (tid < TAIL)
        vt = __builtin_nontemporal_load(gbase + tid + 256 * FULL);

    __builtin_amdgcn_sched_barrier(0);   // keep the load batch intact

    // ---- branch-free nibble-mask build (slot k = int4 tid+256k) ----
    unsigned n0 = 0u, n1 = 0u;
    #pragma unroll
    for (int k = 0; k < 8; ++k)
        n0 |= nib(v[k]) << (4 * k);
    #pragma unroll
    for (int k = 8; k < FULL; ++k)
        n1 |= nib(v[k]) << (4 * (k - 8));
    n1 |= nib(vt) << (4 * (FULL - 8));   // tail in slot 11 (zero if tid>=TAIL)

    // ---- deposit hits into LDS bitmap (ds_or, fire-and-forget) ----
    #pragma unroll
    for (int half = 0; half < 2; ++half) {
        unsigned w = half ? n1 : n0;
        const int kbase = half ? 8 : 0;
        while (w) {
            const int b = __builtin_ctz(w);
            w &= w - 1;
            const int k = kbase + (b >> 2);
            const unsigned g   = (unsigned)(tid + 256 * k) * 4u + (unsigned)(b & 3);
            const unsigned row = __umulhi(g, MAGIC181);   // g / 181
            const unsigned cls = g - 181u * row;          // g % 181
            atomicOr(&bm[row * 8u + (cls >> 5u)], 1u << (cls & 31u));
        }
    }
    __syncthreads();

    // ---- phase 3: wave 0, one row per lane ----
    if (tid < RPB) {
        const float doa[4] = {d0, d1, d2, d3};

        float ang[4];
        int found = 0;
        #pragma unroll
        for (int k = 0; k < 8; ++k) {
            unsigned mm = bm[tid * 8 + k];
            while (mm) {
                const int j = __builtin_ctz(mm);
                mm &= mm - 1;
                ang[found & 3] = ((float)(k * 32 + j) - 90.0f) * DEG2RAD;
                ++found;
            }
        }

        float cst[4][4];
        #pragma unroll
        for (int i = 0; i < 4; ++i)
            #pragma unroll
            for (int j = 0; j < 4; ++j)
                cst[i][j] = sq_mod_diff(doa[i] - ang[j]);

        float best = 1e30f;
        #pragma unroll
        for (int a = 0; a < 4; ++a) {
            #pragma unroll
            for (int b = 0; b < 4; ++b) {
                if (b == a) continue;
                const float top = cst[0][a] + cst[1][b];
                #pragma unroll
                for (int e = 0; e < 4; ++e) {
                    if (e == a || e == b) continue;
                    const int f = 6 - a - b - e;
                    best = fminf(best, top + cst[2][e] + cst[3][f]);
                }
            }
        }
        float sum = sqrtf(best * 0.25f);

        // wave 0 reduce (64 fully-active lanes) -> one atomic per block
        #pragma unroll
        for (int off = 32; off > 0; off >>= 1)
            sum += __shfl_down(sum, off);
        if (lane == 0)
            atomicAdd(out, sum * (1.0f / (float)BATCH));   // 2048 atomics
    }
}

extern "C" void kernel_launch(void* const* d_in, const int* in_sizes, int n_in,
                              void* d_out, int out_size, void* d_ws, size_t ws_size,
                              hipStream_t stream) {
    const float* logits = (const float*)d_in[0];
    const int*   labels = (const int*)d_in[1];
    float*       out    = (float*)d_out;

    // d_out is poisoned (0xAA) before every launch — zero it first.
    hipMemsetAsync(out, 0, sizeof(float), stream);

    // BATCH / RPB = 2048 blocks x 256 threads
    fused_kernel<<<BATCH / RPB, 256, 0, stream>>>(logits, labels, out);
}